// Round 1
// baseline (17227.992 us; speedup 1.0000x reference)
//
#include <hip/hip_runtime.h>
#include <hip/hip_bf16.h>

// Problem constants
#define SEQ   512
#define BATCH 64
#define DIN   1024
#define DH    1024
#define NBLK  256   // one block per JT hidden units
#define JT    4     // hidden units owned per block
#define NT    16    // gate rows per block (4 gates * JT)

typedef unsigned short u16;
typedef __attribute__((ext_vector_type(8))) short   short8;   // 8 x bf16 MFMA operand
typedef __attribute__((ext_vector_type(4))) float   floatx4;  // MFMA accumulator
typedef __attribute__((ext_vector_type(8))) unsigned short ushort8;

static __device__ __forceinline__ u16 f2bf(float f) {
    union { float f; unsigned u; } v; v.f = f;
    unsigned r = v.u + 0x7fffu + ((v.u >> 16) & 1u);   // RNE
    return (u16)(r >> 16);
}

static __device__ __forceinline__ float sigmoid_f(float x) {
    return 1.0f / (1.0f + __expf(-x));
}

static __device__ __forceinline__ float tanh_f(float x) {
    x = fminf(10.0f, fmaxf(-10.0f, x));
    float e = __expf(2.0f * x);
    return (e - 1.0f) / (e + 1.0f);
}

// ---- pre-pass: fp32 -> bf16 cast of X (vectorized) ----
__global__ void cvt_bf16(const float* __restrict__ x, u16* __restrict__ o, int n8) {
    int i = blockIdx.x * blockDim.x + threadIdx.x;
    if (i >= n8) return;
    const float4* xp = (const float4*)x;
    float4 a = xp[2 * i], b = xp[2 * i + 1];
    ushort8 r;
    r[0] = f2bf(a.x); r[1] = f2bf(a.y); r[2] = f2bf(a.z); r[3] = f2bf(a.w);
    r[4] = f2bf(b.x); r[5] = f2bf(b.y); r[6] = f2bf(b.z); r[7] = f2bf(b.w);
    ((ushort8*)o)[i] = r;
}

// ---- persistent LSTM kernel: whole sequence in one launch ----
// Block b owns hidden units j in [4b, 4b+4) -> 16 gate rows [f0..f3,i0..i3,g0..g3,o0..o3].
// Wx/Wh slices live in LDS in MFMA B-fragment order. One grid barrier per step.
__global__ void __launch_bounds__(256) lstm_persist(
    const float* __restrict__ X,    // (SEQ*BATCH, DIN) fp32
    const u16*   __restrict__ Xb,   // same, bf16 (may be unused)
    int x_bf16,
    const float* __restrict__ Wf, const float* __restrict__ Wi,
    const float* __restrict__ Wg, const float* __restrict__ Wo,
    const float* __restrict__ bfp, const float* __restrict__ bip,
    const float* __restrict__ bgp, const float* __restrict__ bop,
    float* __restrict__ out,        // outputs(SEQ,B,DH) ++ h_n(B,DH) ++ c_n(B,DH)
    u16*   __restrict__ hbuf,       // 2 * (BATCH*DH) bf16, pre-zeroed
    unsigned* __restrict__ bar)     // monotonic barrier counter, pre-zeroed
{
    __shared__ u16 Wx_l[32 * 64 * 8];   // 32 KiB: B-frags [kk][lane][8]
    __shared__ u16 Wh_l[32 * 64 * 8];   // 32 KiB
    __shared__ float G[4][16][17];      // gate preactivations, +1 pad
    __shared__ float biasL[16];

    const int tid = threadIdx.x;
    const int j0  = blockIdx.x * JT;

    if (tid < 16) {
        int gate = tid >> 2, jj = tid & 3;
        const float* bp = gate == 0 ? bfp : gate == 1 ? bip : gate == 2 ? bgp : bop;
        biasL[tid] = bp[j0 + jj];
    }
    // Fill W fragments (one-time). Frag element (kk,lane,j) = W[n][k],
    // n = lane&15 (gate row), k = kk*32 + (lane>>4)*8 + j.
    for (int idx = tid; idx < 32 * 64 * 8; idx += 256) {
        int kk   = idx >> 9;
        int rem  = idx & 511;
        int lane = rem >> 3, j = rem & 7;
        int n  = lane & 15, kq = lane >> 4;
        int k  = kk * 32 + kq * 8 + j;
        int gate = n >> 2, jj = n & 3;
        const float* Wp = gate == 0 ? Wf : gate == 1 ? Wi : gate == 2 ? Wg : Wo;
        const float* row = Wp + (size_t)(j0 + jj) * (DIN + DH);
        Wx_l[idx] = f2bf(row[k]);
        Wh_l[idx] = f2bf(row[DIN + k]);
    }
    __syncthreads();

    const int lane = tid & 63;
    const int w    = tid >> 6;       // wave 0..3 -> batch rows [16w,16w+16)
    const int am   = lane & 15;      // A-frag row (batch within wave tile)
    const int kq   = lane >> 4;      // A/B-frag k-quad
    const int row_glob = w * 16 + am;

    // pointwise ownership: one (batch, jj) per thread; c stays in fp32 register
    const int eb  = tid & 63;
    const int ejj = tid >> 6;
    const int jglob = j0 + ejj;
    float c = 0.0f;

    const short8* WxF = (const short8*)Wx_l;
    const short8* WhF = (const short8*)Wh_l;

    for (int t = 0; t < SEQ; ++t) {
        floatx4 accx = {0.f, 0.f, 0.f, 0.f};
        floatx4 acch = {0.f, 0.f, 0.f, 0.f};
        const u16* hprev = hbuf + ((t - 1) & 1) * (BATCH * DH) + row_glob * DH + kq * 8;

        if (x_bf16) {
            const u16* xrow = Xb + ((size_t)t * BATCH + row_glob) * DIN + kq * 8;
            #pragma unroll 8
            for (int kk = 0; kk < 32; ++kk) {
                short8 ax = *(const short8*)(xrow + kk * 32);
                short8 ah = *(const short8*)(hprev + kk * 32);
                accx = __builtin_amdgcn_mfma_f32_16x16x32_bf16(ax, WxF[kk * 64 + lane], accx, 0, 0, 0);
                acch = __builtin_amdgcn_mfma_f32_16x16x32_bf16(ah, WhF[kk * 64 + lane], acch, 0, 0, 0);
            }
        } else {
            const float* xrow = X + ((size_t)t * BATCH + row_glob) * DIN + kq * 8;
            #pragma unroll 4
            for (int kk = 0; kk < 32; ++kk) {
                float4 a0 = *(const float4*)(xrow + kk * 32);
                float4 a1 = *(const float4*)(xrow + kk * 32 + 4);
                short8 ax;
                ax[0] = (short)f2bf(a0.x); ax[1] = (short)f2bf(a0.y);
                ax[2] = (short)f2bf(a0.z); ax[3] = (short)f2bf(a0.w);
                ax[4] = (short)f2bf(a1.x); ax[5] = (short)f2bf(a1.y);
                ax[6] = (short)f2bf(a1.z); ax[7] = (short)f2bf(a1.w);
                short8 ah = *(const short8*)(hprev + kk * 32);
                accx = __builtin_amdgcn_mfma_f32_16x16x32_bf16(ax, WxF[kk * 64 + lane], accx, 0, 0, 0);
                acch = __builtin_amdgcn_mfma_f32_16x16x32_bf16(ah, WhF[kk * 64 + lane], acch, 0, 0, 0);
            }
        }
        floatx4 acc = accx + acch;

        // C/D layout: col = lane&15 (gate n), row = (lane>>4)*4 + q (batch in wave)
        #pragma unroll
        for (int q = 0; q < 4; ++q)
            G[w][kq * 4 + q][lane & 15] = acc[q];
        __syncthreads();

        {
            int w2 = eb >> 4, r2 = eb & 15;
            float pf = G[w2][r2][ejj]      + biasL[ejj];
            float pi = G[w2][r2][4 + ejj]  + biasL[4 + ejj];
            float pg = G[w2][r2][8 + ejj]  + biasL[8 + ejj];
            float po = G[w2][r2][12 + ejj] + biasL[12 + ejj];
            float fg = sigmoid_f(pf);
            float ig = sigmoid_f(pi);
            float gg = tanh_f(pg);
            float og = sigmoid_f(po);
            c = fg * c + ig * gg;
            float h = og * tanh_f(c);
            out[(size_t)t * (BATCH * DH) + eb * DH + jglob] = h;
            hbuf[(t & 1) * (BATCH * DH) + eb * DH + jglob] = f2bf(h);
            if (t == SEQ - 1) {
                out[(size_t)SEQ * BATCH * DH + eb * DH + jglob] = h;                 // h_n
                out[(size_t)SEQ * BATCH * DH + BATCH * DH + eb * DH + jglob] = c;    // c_n
            }
        }

        // grid barrier (skip after last step)
        __syncthreads();
        if (t < SEQ - 1) {
            if (tid == 0) {
                __threadfence();
                __hip_atomic_fetch_add(bar, 1u, __ATOMIC_RELEASE, __HIP_MEMORY_SCOPE_AGENT);
                unsigned target = (unsigned)(t + 1) * (unsigned)NBLK;
                while (__hip_atomic_load(bar, __ATOMIC_ACQUIRE, __HIP_MEMORY_SCOPE_AGENT) < target) {
                    __builtin_amdgcn_s_sleep(1);
                }
            }
            __syncthreads();
        }
    }
}

extern "C" void kernel_launch(void* const* d_in, const int* in_sizes, int n_in,
                              void* d_out, int out_size, void* d_ws, size_t ws_size,
                              hipStream_t stream) {
    const float* X   = (const float*)d_in[0];
    const float* Wf  = (const float*)d_in[1];
    const float* bfv = (const float*)d_in[2];
    const float* Wi  = (const float*)d_in[3];
    const float* biv = (const float*)d_in[4];
    const float* Wg  = (const float*)d_in[5];
    const float* bgv = (const float*)d_in[6];
    const float* Wo  = (const float*)d_in[7];
    const float* bov = (const float*)d_in[8];
    float* out = (float*)d_out;

    unsigned char* ws = (unsigned char*)d_ws;
    u16* hbuf     = (u16*)ws;                       // 2 * 64*1024 * 2 B = 256 KiB
    unsigned* bar = (unsigned*)(ws + (256 << 10));  // 4 B counter
    u16* Xb       = (u16*)(ws + (1 << 20));         // 64 MiB bf16 X (optional)

    size_t need = (size_t)(1 << 20) + (size_t)SEQ * BATCH * DIN * 2;
    int x_bf16 = (ws_size >= need) ? 1 : 0;

    // zero h double-buffer + barrier counter (re-poisoned to 0xAA before each launch)
    hipMemsetAsync(ws, 0, (256 << 10) + 256, stream);

    if (x_bf16) {
        int n8 = SEQ * BATCH * DIN / 8;
        cvt_bf16<<<n8 / 256, 256, 0, stream>>>(X, Xb, n8);
    }

    lstm_persist<<<NBLK, 256, 0, stream>>>(
        X, Xb, x_bf16, Wf, Wi, Wg, Wo, bfv, biv, bgv, bov, out, hbuf, bar);
}

// Round 2
// 6050.195 us; speedup vs baseline: 2.8475x; 2.8475x over previous
//
#include <hip/hip_runtime.h>
#include <hip/hip_bf16.h>

// Problem constants
#define SEQ   512
#define BATCH 64
#define DIN   1024
#define DH    1024
#define NBLK  256   // one block per JT hidden units
#define JT    4     // hidden units owned per block

typedef unsigned short u16;
typedef __attribute__((ext_vector_type(8))) short   short8;   // 8 x bf16 MFMA operand
typedef __attribute__((ext_vector_type(4))) short   short4v;
typedef __attribute__((ext_vector_type(4))) float   floatx4;  // MFMA accumulator
typedef __attribute__((ext_vector_type(2))) unsigned int uint2v;

static __device__ __forceinline__ u16 f2bf(float f) {
    union { float f; unsigned u; } v; v.f = f;
    unsigned r = v.u + 0x7fffu + ((v.u >> 16) & 1u);   // RNE
    return (u16)(r >> 16);
}

static __device__ __forceinline__ float sigmoid_f(float x) {
    return 1.0f / (1.0f + __expf(-x));
}

static __device__ __forceinline__ float tanh_f(float x) {
    x = fminf(10.0f, fmaxf(-10.0f, x));
    float e = __expf(2.0f * x);
    return (e - 1.0f) / (e + 1.0f);
}

// Build a bf16 A-fragment from 8 consecutive fp32 (on-the-fly cast).
static __device__ __forceinline__ short8 xfrag(const float* xr) {
    float4 a0 = *(const float4*)xr;
    float4 a1 = *(const float4*)(xr + 4);
    short8 ax;
    ax[0] = (short)f2bf(a0.x); ax[1] = (short)f2bf(a0.y);
    ax[2] = (short)f2bf(a0.z); ax[3] = (short)f2bf(a0.w);
    ax[4] = (short)f2bf(a1.x); ax[5] = (short)f2bf(a1.y);
    ax[6] = (short)f2bf(a1.z); ax[7] = (short)f2bf(a1.w);
    return ax;
}

// HIST=1: 512-deep h history (no address reuse -> cached reads are always fresh),
//         sc0sc1 write-through h stores, relaxed barrier (no cache flush ops).
// HIST=0: fallback double-buffer + fenced barrier (round-1 semantics, slow but
//         correct with tiny workspace).
template <int HIST>
__global__ void __launch_bounds__(256) lstm_persist(
    const float* __restrict__ X,
    const float* __restrict__ Wf, const float* __restrict__ Wi,
    const float* __restrict__ Wg, const float* __restrict__ Wo,
    const float* __restrict__ bfp, const float* __restrict__ bip,
    const float* __restrict__ bgp, const float* __restrict__ bop,
    float* __restrict__ out,        // outputs(SEQ,B,DH) ++ h_n(B,DH) ++ c_n(B,DH)
    u16*   __restrict__ hbuf,       // block-major: [t][blk*256 + b*4 + jj]
    unsigned* __restrict__ cnt)     // 8 counters, 64 B apart, pre-zeroed
{
    __shared__ u16 Wx_l[32 * 64 * 8];   // 32 KiB B-frags [kk][lane][8]
    __shared__ u16 Wh_l[32 * 64 * 8];   // 32 KiB
    __shared__ float G[4][16][20];      // gate preactivations; stride 20 -> 16B-aligned rows
    __shared__ float biasL[16];

    const int tid = threadIdx.x;
    const int blk = blockIdx.x;
    const int j0  = blk * JT;

    if (tid < 16) {
        int gate = tid >> 2, jj = tid & 3;
        const float* bp = gate == 0 ? bfp : gate == 1 ? bip : gate == 2 ? bgp : bop;
        biasL[tid] = bp[j0 + jj];
    }
    // One-time W fragment fill. Frag element (kk,lane,j) = W[n][k],
    // n = lane&15 (gate row = gate*4+jj), k = kk*32 + (lane>>4)*8 + j.
    for (int idx = tid; idx < 32 * 64 * 8; idx += 256) {
        int kk   = idx >> 9;
        int rem  = idx & 511;
        int lane_f = rem >> 3, j = rem & 7;
        int n  = lane_f & 15, kqf = lane_f >> 4;
        int k  = kk * 32 + kqf * 8 + j;
        int gate = n >> 2, jj = n & 3;
        const float* Wp = gate == 0 ? Wf : gate == 1 ? Wi : gate == 2 ? Wg : Wo;
        const float* row = Wp + (size_t)(j0 + jj) * (DIN + DH);
        Wx_l[idx] = f2bf(row[k]);
        Wh_l[idx] = f2bf(row[DIN + k]);
    }
    __syncthreads();

    const int lane = tid & 63;
    const int w    = tid >> 6;          // wave id; wave w owns batch rows [16w,16w+16)
    const int kq   = lane >> 4;         // k-quad within fragment
    const int row_glob = w * 16 + (lane & 15);

    // Pointwise: wave 0 only; thread `lane` owns batch b=lane, hidden j0..j0+3.
    float c[4] = {0.f, 0.f, 0.f, 0.f};
    float4 bF4, bI4, bG4, bO4;
    if (w == 0) {
        bF4 = *(const float4*)&biasL[0];
        bI4 = *(const float4*)&biasL[4];
        bG4 = *(const float4*)&biasL[8];
        bO4 = *(const float4*)&biasL[12];
    }

    const short8* WxF = (const short8*)Wx_l;
    const short8* WhF = (const short8*)Wh_l;

    // Prologue: x-projection for t=0 (two independent MFMA chains).
    floatx4 accx0 = {0.f, 0.f, 0.f, 0.f}, accx1 = {0.f, 0.f, 0.f, 0.f};
    {
        const float* xr = X + (size_t)row_glob * DIN + kq * 8;
        #pragma unroll 4
        for (int kk = 0; kk < 32; kk += 2) {
            accx0 = __builtin_amdgcn_mfma_f32_16x16x32_bf16(xfrag(xr + kk * 32),       WxF[kk * 64 + lane],       accx0, 0, 0, 0);
            accx1 = __builtin_amdgcn_mfma_f32_16x16x32_bf16(xfrag(xr + (kk + 1) * 32), WxF[(kk + 1) * 64 + lane], accx1, 0, 0, 0);
        }
    }

    for (int t = 0; t < SEQ; ++t) {
        // ---- recurrent chain: h(t-1) @ Wh ----
        floatx4 acch0 = {0.f, 0.f, 0.f, 0.f}, acch1 = {0.f, 0.f, 0.f, 0.f};
        if (t > 0) {
            const u16* hb = hbuf + (size_t)(HIST ? (t - 1) : ((t - 1) & 1)) * (BATCH * DH)
                            + row_glob * 4;
            #pragma unroll 4
            for (int kk = 0; kk < 32; kk += 2) {
                short4v l0 = *(const short4v*)(hb + (kq * 2 + kk * 8) * 256);
                short4v m0 = *(const short4v*)(hb + (kq * 2 + kk * 8 + 1) * 256);
                short8 a0 = __builtin_shufflevector(l0, m0, 0, 1, 2, 3, 4, 5, 6, 7);
                acch0 = __builtin_amdgcn_mfma_f32_16x16x32_bf16(a0, WhF[kk * 64 + lane], acch0, 0, 0, 0);
                short4v l1 = *(const short4v*)(hb + (kq * 2 + (kk + 1) * 8) * 256);
                short4v m1 = *(const short4v*)(hb + (kq * 2 + (kk + 1) * 8 + 1) * 256);
                short8 a1 = __builtin_shufflevector(l1, m1, 0, 1, 2, 3, 4, 5, 6, 7);
                acch1 = __builtin_amdgcn_mfma_f32_16x16x32_bf16(a1, WhF[(kk + 1) * 64 + lane], acch1, 0, 0, 0);
            }
        }
        floatx4 acc = (accx0 + accx1) + (acch0 + acch1);

        // C/D layout: col = lane&15 (gate row n), row = kq*4+q (batch within wave tile)
        #pragma unroll
        for (int q = 0; q < 4; ++q)
            G[w][kq * 4 + q][lane & 15] = acc[q];
        __syncthreads();

        // ---- pointwise update (wave 0), then arrive at barrier ----
        if (w == 0) {
            const float* Gr = &G[lane >> 4][lane & 15][0];
            float4 vF = *(const float4*)(Gr);
            float4 vI = *(const float4*)(Gr + 4);
            float4 vG = *(const float4*)(Gr + 8);
            float4 vO = *(const float4*)(Gr + 12);
            float pf[4], pi[4], pg[4], po[4], h[4];
            *(float4*)pf = vF; *(float4*)pi = vI; *(float4*)pg = vG; *(float4*)po = vO;
            const float* bFp = (const float*)&bF4; const float* bIp = (const float*)&bI4;
            const float* bGp = (const float*)&bG4; const float* bOp = (const float*)&bO4;
            #pragma unroll
            for (int j = 0; j < 4; ++j) {
                float F  = sigmoid_f(pf[j] + bFp[j]);
                float I  = sigmoid_f(pi[j] + bIp[j]);
                float Gg = tanh_f(pg[j] + bGp[j]);
                float O  = sigmoid_f(po[j] + bOp[j]);
                c[j] = F * c[j] + I * Gg;
                h[j] = O * tanh_f(c[j]);
            }
            float4 ho = {h[0], h[1], h[2], h[3]};
            *(float4*)(out + (size_t)t * (BATCH * DH) + (size_t)lane * DH + j0) = ho;
            if (t == SEQ - 1) {
                *(float4*)(out + (size_t)SEQ * (BATCH * DH) + (size_t)lane * DH + j0) = ho;
                float4 co = {c[0], c[1], c[2], c[3]};
                *(float4*)(out + (size_t)SEQ * (BATCH * DH) + (BATCH * DH) + (size_t)lane * DH + j0) = co;
            } else {
                // block-major h store: block's 512 B region is exclusively ours
                u16* dst = hbuf + (size_t)(HIST ? t : (t & 1)) * (BATCH * DH) + blk * 256 + lane * 4;
                uint2v hv;
                hv[0] = (unsigned)f2bf(h[0]) | ((unsigned)f2bf(h[1]) << 16);
                hv[1] = (unsigned)f2bf(h[2]) | ((unsigned)f2bf(h[3]) << 16);
                if (HIST) {
                    asm volatile("global_store_dwordx2 %0, %1, off sc0 sc1"
                                 :: "v"(dst), "v"(hv) : "memory");
                } else {
                    *(uint2v*)dst = hv;
                }
            }
        }

        if (t < SEQ - 1) {
            // arrive: h stores visible device-wide, then bump counter
            if (HIST) {
                if (w == 0) {
                    asm volatile("s_waitcnt vmcnt(0)" ::: "memory");
                    if (lane == 0)
                        (void)__hip_atomic_fetch_add(&cnt[(blk & 7) * 16], 1u,
                                                     __ATOMIC_RELAXED, __HIP_MEMORY_SCOPE_AGENT);
                }
            } else {
                if (tid == 0) {
                    __threadfence();
                    (void)__hip_atomic_fetch_add(&cnt[(blk & 7) * 16], 1u,
                                                 __ATOMIC_RELEASE, __HIP_MEMORY_SCOPE_AGENT);
                }
            }

            // x-projection for t+1 — independent of h, overlaps barrier skew
            accx0 = (floatx4){0.f, 0.f, 0.f, 0.f};
            accx1 = (floatx4){0.f, 0.f, 0.f, 0.f};
            {
                const float* xr = X + ((size_t)(t + 1) * BATCH + row_glob) * DIN + kq * 8;
                #pragma unroll 4
                for (int kk = 0; kk < 32; kk += 2) {
                    accx0 = __builtin_amdgcn_mfma_f32_16x16x32_bf16(xfrag(xr + kk * 32),       WxF[kk * 64 + lane],       accx0, 0, 0, 0);
                    accx1 = __builtin_amdgcn_mfma_f32_16x16x32_bf16(xfrag(xr + (kk + 1) * 32), WxF[(kk + 1) * 64 + lane], accx1, 0, 0, 0);
                }
            }

            // poll: 8 threads, one counter each; relaxed (no cache invalidates)
            unsigned target = (unsigned)(t + 1) * 32u;
            if (tid < 8) {
                if (HIST) {
                    while (__hip_atomic_load(&cnt[tid * 16], __ATOMIC_RELAXED,
                                             __HIP_MEMORY_SCOPE_AGENT) < target)
                        __builtin_amdgcn_s_sleep(1);
                } else {
                    while (__hip_atomic_load(&cnt[tid * 16], __ATOMIC_ACQUIRE,
                                             __HIP_MEMORY_SCOPE_AGENT) < target)
                        __builtin_amdgcn_s_sleep(1);
                }
            }
            asm volatile("" ::: "memory");
            __syncthreads();
        }
    }
}

extern "C" void kernel_launch(void* const* d_in, const int* in_sizes, int n_in,
                              void* d_out, int out_size, void* d_ws, size_t ws_size,
                              hipStream_t stream) {
    (void)in_sizes; (void)n_in; (void)out_size;
    const float* X   = (const float*)d_in[0];
    const float* Wf  = (const float*)d_in[1];
    const float* bfv = (const float*)d_in[2];
    const float* Wi  = (const float*)d_in[3];
    const float* biv = (const float*)d_in[4];
    const float* Wg  = (const float*)d_in[5];
    const float* bgv = (const float*)d_in[6];
    const float* Wo  = (const float*)d_in[7];
    const float* bov = (const float*)d_in[8];
    float* out = (float*)d_out;

    unsigned char* ws = (unsigned char*)d_ws;
    unsigned* cnt = (unsigned*)ws;              // 8 counters, 64 B apart
    u16* hbuf     = (u16*)(ws + 4096);

    // zero counters (ws is re-poisoned to 0xAA before every timed launch)
    hipMemsetAsync(ws, 0, 4096, stream);

    const size_t need_hist = 4096 + (size_t)SEQ * BATCH * DH * 2;   // 64 MiB + 4 KiB
    if (ws_size >= need_hist) {
        lstm_persist<1><<<NBLK, 256, 0, stream>>>(
            X, Wf, Wi, Wg, Wo, bfv, biv, bgv, bov, out, hbuf, cnt);
    } else {
        lstm_persist<0><<<NBLK, 256, 0, stream>>>(
            X, Wf, Wi, Wg, Wo, bfv, biv, bgv, bov, out, hbuf, cnt);
    }
}